// Round 5
// baseline (588.465 us; speedup 1.0000x reference)
//
#include <hip/hip_runtime.h>

constexpr int NN = 40000;
constexpr int NE = 640000;
constexpr int NBKT = 625;      // bucket = dst >> 6, 64 nodes per bucket

typedef __attribute__((ext_vector_type(8))) short short8;
typedef __attribute__((ext_vector_type(4))) float f32x4;

// f32 -> bf16 round-to-nearest-even
__device__ __forceinline__ unsigned short rneb(float f) {
    unsigned u = __float_as_uint(f);
    u = (u + 0x7FFFu + ((u >> 16) & 1u)) >> 16;
    return (unsigned short)u;
}
__device__ __forceinline__ float b2f(unsigned short s) {
    return __uint_as_float(((unsigned)s) << 16);
}

// ---------- zero the 625 global bucket counters (replaces hipMemsetAsync node) ----------
__global__ void zero_k(int* __restrict__ g) {
    int t = threadIdx.x;
    if (t < NBKT) g[t] = 0;
}

// ---------- x f32 -> xb bf16 ----------
__global__ __launch_bounds__(256) void cvtx_k(const float* __restrict__ x,
                                              unsigned short* __restrict__ xb) {
    int g = blockIdx.x * 256 + threadIdx.x;      // 1.28M float4-groups
    float4 v = reinterpret_cast<const float4*>(x)[g];
    ushort4 o = { rneb(v.x), rneb(v.y), rneb(v.z), rneb(v.w) };
    reinterpret_cast<ushort4*>(xb)[g] = o;
}

// ---------- W f32 -> Wb bf16 ----------
__global__ void cvtw_k(const float* __restrict__ W, unsigned short* __restrict__ Wb) {
    int g = blockIdx.x * 256 + threadIdx.x;      // 8192 float4-groups
    if (g >= 128 * 64) return;
    float4 v = reinterpret_cast<const float4*>(W)[g];
    ushort4 o = { rneb(v.x), rneb(v.y), rneb(v.z), rneb(v.w) };
    reinterpret_cast<ushort4*>(Wb)[g] = o;
}

// ---------- coarse bucket count: 128 blocks x 5000 edges ----------
__global__ __launch_bounds__(1024) void ccount_k(const int* __restrict__ dst,
                                                 int* __restrict__ gcnt) {
    __shared__ int cnt[NBKT];
    int t = threadIdx.x;
    if (t < NBKT) cnt[t] = 0;
    __syncthreads();
    int eb = blockIdx.x * 5000;
    for (int i = t; i < 5000; i += 1024)
        atomicAdd(&cnt[dst[eb + i] >> 6], 1);
    __syncthreads();
    if (t < NBKT && cnt[t]) atomicAdd(&gcnt[t], cnt[t]);
}

// ---------- exclusive scan of 625 bucket counts -> bptr[626], cursor[625] ----------
__global__ __launch_bounds__(1024) void cscan_k(const int* __restrict__ gcnt,
                                                int* __restrict__ bptr,
                                                int* __restrict__ cursor) {
    __shared__ int sc[1024];
    int t = threadIdx.x;
    int c = (t < NBKT) ? gcnt[t] : 0;
    sc[t] = c;
    __syncthreads();
    for (int o = 1; o < 1024; o <<= 1) {
        int u = (t >= o) ? sc[t - o] : 0;
        __syncthreads();
        sc[t] += u;
        __syncthreads();
    }
    if (t < NBKT) {
        int excl = sc[t] - c;
        bptr[t]   = excl;
        cursor[t] = excl;
    }
    if (t == 0) bptr[NBKT] = NE;
}

// ---------- bucket scatter: rec {src u16 | ew f16}, dloc u8 ----------
__global__ __launch_bounds__(1024) void cscatter_k(const int* __restrict__ dst,
                                                   const int* __restrict__ src,
                                                   const float* __restrict__ ew,
                                                   int* __restrict__ cursor,
                                                   unsigned* __restrict__ rec,
                                                   unsigned char* __restrict__ dloc) {
    __shared__ int cnt[NBKT];
    __shared__ int base[NBKT];
    int t = threadIdx.x;
    if (t < NBKT) cnt[t] = 0;
    __syncthreads();
    int eb = blockIdx.x * 5000;
    for (int i = t; i < 5000; i += 1024)
        atomicAdd(&cnt[dst[eb + i] >> 6], 1);
    __syncthreads();
    if (t < NBKT) {
        base[t] = atomicAdd(&cursor[t], cnt[t]);   // reserve contiguous run
        cnt[t]  = 0;                               // reuse as local cursor
    }
    __syncthreads();
    for (int i = t; i < 5000; i += 1024) {
        int d   = dst[eb + i];
        int bkt = d >> 6;
        int slot = atomicAdd(&cnt[bkt], 1);
        int p = base[bkt] + slot;
        unsigned short wh = __builtin_bit_cast(unsigned short, (_Float16)ew[eb + i]);
        rec[p]  = (unsigned)src[eb + i] | ((unsigned)wh << 16);
        dloc[p] = (unsigned char)(d & 63);
    }
}

// ---------- fused aggregate: one block per bucket, LDS f32 accumulators ----------
// agg written as f32 into d_out (gemm reads its own rows before overwriting them).
__global__ __launch_bounds__(1024) void agg2_k(const unsigned* __restrict__ rec,
                                               const unsigned char* __restrict__ dloc,
                                               const int* __restrict__ bptr,
                                               const unsigned short* __restrict__ xb,
                                               float* __restrict__ out) {
    __shared__ float accum[64][129];     // +1 pad: odd stride breaks bank alignment
    __shared__ float wsumL[64];
    int bkt = blockIdx.x, t = threadIdx.x;
    for (int i = t; i < 64 * 129; i += 1024) (&accum[0][0])[i] = 0.f;
    if (t < 64) wsumL[t] = 0.f;
    __syncthreads();
    int beg = bptr[bkt], end = bptr[bkt + 1];
    int grp = t >> 4, fl = t & 15;       // 64 edge-groups x 16 feature-lanes
    for (int e = beg + grp; e < end; e += 64) {
        unsigned r = rec[e];
        int s = r & 0xFFFF;
        float w = (float)__builtin_bit_cast(_Float16, (unsigned short)(r >> 16));
        int d = dloc[e];
        short8 v = *reinterpret_cast<const short8*>(xb + (size_t)s * 128 + fl * 8);
        #pragma unroll
        for (int i = 0; i < 8; ++i)
            atomicAdd(&accum[d][fl * 8 + i], w * b2f((unsigned short)v[i]));
        if (fl == 0) atomicAdd(&wsumL[d], w);
    }
    __syncthreads();
    int nb = bkt * 64;
    for (int u = t; u < 64 * 32; u += 1024) {
        int d = u >> 5, c4 = u & 31;
        float inv = 1.f / fmaxf(wsumL[d], 1e-8f);
        float4 o = { accum[d][c4 * 4 + 0] * inv, accum[d][c4 * 4 + 1] * inv,
                     accum[d][c4 * 4 + 2] * inv, accum[d][c4 * 4 + 3] * inv };
        reinterpret_cast<float4*>(out)[(size_t)(nb + d) * 32 + c4] = o;
    }
}

// ---------- MFMA GEMM: out = [xb | agg(in out, f32)] @ Wb^T + b ----------
// Each block owns rows [rb, rb+128): reads agg only from its own rows, then
// overwrites them -> no cross-block race.
__global__ __launch_bounds__(256) void gemm_mfma_k(const unsigned short* __restrict__ xb,
                                                   const unsigned short* __restrict__ Wb,
                                                   const float* __restrict__ bias_p,
                                                   float* out) {
    int w = threadIdx.x >> 6, l = threadIdx.x & 63;
    int l15 = l & 15, lg = l >> 4;
    int rb = blockIdx.x * 128 + w * 32;

    f32x4 acc[2][8];
    #pragma unroll
    for (int i = 0; i < 2; ++i)
        #pragma unroll
        for (int c = 0; c < 8; ++c) acc[i][c] = (f32x4)0.f;

    float bias[8];
    #pragma unroll
    for (int c = 0; c < 8; ++c) bias[c] = bias_p[c * 16 + l15];

    int r0 = rb + l15;      if (r0 > NN - 1) r0 = NN - 1;
    int r1 = rb + 16 + l15; if (r1 > NN - 1) r1 = NN - 1;

    #pragma unroll
    for (int step = 0; step < 8; ++step) {
        int kg = step * 32 + lg * 8;
        short8 a0, a1;
        if (step < 4) {
            a0 = *reinterpret_cast<const short8*>(xb + (size_t)r0 * 128 + kg);
            a1 = *reinterpret_cast<const short8*>(xb + (size_t)r1 * 128 + kg);
        } else {
            const float* p0 = out + (size_t)r0 * 128 + (kg - 128);
            const float* p1 = out + (size_t)r1 * 128 + (kg - 128);
            float4 u0 = *reinterpret_cast<const float4*>(p0);
            float4 u1 = *reinterpret_cast<const float4*>(p0 + 4);
            float4 v0 = *reinterpret_cast<const float4*>(p1);
            float4 v1 = *reinterpret_cast<const float4*>(p1 + 4);
            a0 = short8{ (short)rneb(u0.x), (short)rneb(u0.y), (short)rneb(u0.z), (short)rneb(u0.w),
                         (short)rneb(u1.x), (short)rneb(u1.y), (short)rneb(u1.z), (short)rneb(u1.w) };
            a1 = short8{ (short)rneb(v0.x), (short)rneb(v0.y), (short)rneb(v0.z), (short)rneb(v0.w),
                         (short)rneb(v1.x), (short)rneb(v1.y), (short)rneb(v1.z), (short)rneb(v1.w) };
        }
        #pragma unroll
        for (int c = 0; c < 8; ++c) {
            short8 bf = *reinterpret_cast<const short8*>(Wb + (size_t)(c * 16 + l15) * 256 + kg);
            acc[0][c] = __builtin_amdgcn_mfma_f32_16x16x32_bf16(a0, bf, acc[0][c], 0, 0, 0);
            acc[1][c] = __builtin_amdgcn_mfma_f32_16x16x32_bf16(a1, bf, acc[1][c], 0, 0, 0);
        }
    }

    #pragma unroll
    for (int i = 0; i < 2; ++i) {
        int rbase = rb + i * 16 + lg * 4;
        #pragma unroll
        for (int c = 0; c < 8; ++c) {
            #pragma unroll
            for (int r = 0; r < 4; ++r) {
                int row = rbase + r;
                if (row < NN)
                    out[(size_t)row * 128 + c * 16 + l15] = acc[i][c][r] + bias[c];
            }
        }
    }
}

// ==================== fallback path (small ws): atomic scatter + f32 GEMM ====================

__global__ void wsum_k(const int* __restrict__ dst, const float* __restrict__ ew,
                       float* __restrict__ wsum) {
    int e = blockIdx.x * 256 + threadIdx.x;
    if (e < NE) atomicAdd(&wsum[dst[e]], ew[e]);
}

__global__ void zerof_k(float* __restrict__ p, int n4) {
    int g = blockIdx.x * 256 + threadIdx.x;
    if (g < n4) reinterpret_cast<float4*>(p)[g] = make_float4(0.f, 0.f, 0.f, 0.f);
}

__global__ void scatter_k(const int* __restrict__ src, const int* __restrict__ dst,
                          const float* __restrict__ ew, const float* __restrict__ wsum,
                          const float* __restrict__ x, float* __restrict__ agg) {
    int tid = blockIdx.x * 256 + threadIdx.x;
    int e = tid >> 5;
    int p = tid & 31;
    if (e >= NE) return;
    int s = src[e], dn = dst[e];
    float wn = ew[e] / fmaxf(wsum[dn], 1e-8f);
    float4 v = *reinterpret_cast<const float4*>(x + (size_t)s * 128 + p * 4);
    float* o = agg + (size_t)dn * 128 + p * 4;
    atomicAdd(o + 0, wn * v.x);
    atomicAdd(o + 1, wn * v.y);
    atomicAdd(o + 2, wn * v.z);
    atomicAdd(o + 3, wn * v.w);
}

__global__ __launch_bounds__(256) void gemm_f32_k(const float* __restrict__ x,
                                                  const float* __restrict__ agg,
                                                  const float* __restrict__ W,
                                                  const float* __restrict__ b,
                                                  float* __restrict__ out) {
    __shared__ float4 Wl[128 * 64];
    __shared__ float4 hl[16 * 64];
    int t = threadIdx.x;
    int base = blockIdx.x * 80;
    const float4* Wg = reinterpret_cast<const float4*>(W);
    #pragma unroll
    for (int i = 0; i < 32; ++i) {
        int f = t + i * 256;
        int r = f >> 6, kk = f & 63;
        Wl[r * 64 + (kk ^ (r & 7))] = Wg[f];
    }
    int jj = t & 63, wsl = t >> 6, sw = jj & 7;
    float bv[2] = { b[jj], b[jj + 64] };
    const float4* xg = reinterpret_cast<const float4*>(x);
    const float4* ag = reinterpret_cast<const float4*>(agg);
    for (int g = 0; g < 5; ++g) {
        int nbase = base + g * 16;
        __syncthreads();
        #pragma unroll
        for (int i = 0; i < 4; ++i) {
            int f = t + i * 256;
            int ln = f >> 6, kk = f & 63;
            size_t node = (size_t)(nbase + ln);
            hl[ln * 64 + kk] = (kk < 32) ? xg[node * 32 + kk] : ag[node * 32 + (kk - 32)];
        }
        __syncthreads();
        float acc[2][4];
        #pragma unroll
        for (int q = 0; q < 2; ++q)
            #pragma unroll
            for (int n = 0; n < 4; ++n) acc[q][n] = 0.f;
        #pragma unroll 4
        for (int kk = 0; kk < 64; ++kk) {
            float4 h[4];
            #pragma unroll
            for (int n = 0; n < 4; ++n) h[n] = hl[(wsl + 4 * n) * 64 + kk];
            #pragma unroll
            for (int q = 0; q < 2; ++q) {
                float4 wv = Wl[(jj + q * 64) * 64 + (kk ^ sw)];
                #pragma unroll
                for (int n = 0; n < 4; ++n)
                    acc[q][n] += wv.x * h[n].x + wv.y * h[n].y + wv.z * h[n].z + wv.w * h[n].w;
            }
        }
        #pragma unroll
        for (int q = 0; q < 2; ++q)
            #pragma unroll
            for (int n = 0; n < 4; ++n)
                out[(size_t)(nbase + wsl + 4 * n) * 128 + jj + q * 64] = acc[q][n] + bv[q];
    }
}

extern "C" void kernel_launch(void* const* d_in, const int* in_sizes, int n_in,
                              void* d_out, int out_size, void* d_ws, size_t ws_size,
                              hipStream_t stream) {
    const float* x  = (const float*)d_in[0];
    const int*   ei = (const int*)d_in[1];
    const float* ew = (const float*)d_in[2];
    const float* W  = (const float*)d_in[3];
    const float* b  = (const float*)d_in[4];
    float* out = (float*)d_out;
    const int* src = ei;
    const int* dst = ei + NE;

    // ws layout (bytes):
    //   0        : bptr [626 int]
    //   4096     : cursor [625 int]
    //   8192     : gcnt [625 int]
    //   16384    : Wb [128x256 bf16] (64 KB)
    //   81920    : dloc [640000 u8]
    //   724992   : rec [640000 u32] (2.56 MB)
    //   3284992  : xb [40000][128] bf16 (10.24 MB)
    const size_t off_cursor = 4096;
    const size_t off_gcnt   = 8192;
    const size_t off_Wb     = 16384;
    const size_t off_dloc   = 81920;
    const size_t off_rec    = 724992;
    const size_t off_xb     = 3284992;
    const size_t need = off_xb + (size_t)NN * 128 * 2;

    if (ws_size >= need) {
        int* bptr   = (int*)d_ws;
        int* cursor = (int*)((char*)d_ws + off_cursor);
        int* gcnt   = (int*)((char*)d_ws + off_gcnt);
        unsigned short* Wb = (unsigned short*)((char*)d_ws + off_Wb);
        unsigned char* dloc = (unsigned char*)((char*)d_ws + off_dloc);
        unsigned* rec = (unsigned*)((char*)d_ws + off_rec);
        unsigned short* xb = (unsigned short*)((char*)d_ws + off_xb);

        zero_k    <<<1, 1024, 0, stream>>>(gcnt);
        cvtx_k    <<<5000, 256, 0, stream>>>(x, xb);
        ccount_k  <<<128, 1024, 0, stream>>>(dst, gcnt);
        cscan_k   <<<1, 1024, 0, stream>>>(gcnt, bptr, cursor);
        cscatter_k<<<128, 1024, 0, stream>>>(dst, src, ew, cursor, rec, dloc);
        cvtw_k    <<<32, 256, 0, stream>>>(W, Wb);
        agg2_k    <<<NBKT, 1024, 0, stream>>>(rec, dloc, bptr, xb, out);
        gemm_mfma_k<<<(NN + 127) / 128, 256, 0, stream>>>(xb, Wb, b, out);
    } else {
        float* wsum = (float*)d_ws;
        float* agg  = out;
        zero_k   <<<1, 1024, 0, stream>>>((int*)wsum);   // only first 625 needed? no:
        // wsum needs all 40000 zeroed; use zerof_k for both wsum and agg
        zerof_k  <<<(NN / 4 + 255) / 256, 256, 0, stream>>>(wsum, NN / 4);
        zerof_k  <<<(NN * 32 + 255) / 256, 256, 0, stream>>>(agg, NN * 32);
        wsum_k   <<<(NE + 255) / 256, 256, 0, stream>>>(dst, ew, wsum);
        scatter_k<<<NE * 32 / 256, 256, 0, stream>>>(src, dst, ew, wsum, x, agg);
        gemm_f32_k<<<500, 256, 0, stream>>>(x, agg, W, b, out);
    }
}

// Round 6
// 97.044 us; speedup vs baseline: 6.0639x; 6.0639x over previous
//
#include <hip/hip_runtime.h>

constexpr int NN = 40000;
constexpr int NE = 640000;
constexpr int NBKT = 625;      // bucket = dst >> 6, 64 nodes per bucket

typedef __attribute__((ext_vector_type(8))) short short8;
typedef __attribute__((ext_vector_type(4))) float f32x4;

// f32 -> bf16 round-to-nearest-even
__device__ __forceinline__ unsigned short rneb(float f) {
    unsigned u = __float_as_uint(f);
    u = (u + 0x7FFFu + ((u >> 16) & 1u)) >> 16;
    return (unsigned short)u;
}
__device__ __forceinline__ float b2f(unsigned short s) {
    return __uint_as_float(((unsigned)s) << 16);
}

// ---------- zero the 625 global bucket counters (NO hipMemsetAsync in timed path) ----------
__global__ void zero_k(int* __restrict__ g) {
    int t = threadIdx.x;
    if (t < NBKT) g[t] = 0;
}

// ---------- x f32 -> xb bf16 (dense [40000][128]) ----------
__global__ __launch_bounds__(256) void cvtx_k(const float* __restrict__ x,
                                              unsigned short* __restrict__ xb) {
    int g = blockIdx.x * 256 + threadIdx.x;      // 1.28M float4-groups
    float4 v = reinterpret_cast<const float4*>(x)[g];
    ushort4 o = { rneb(v.x), rneb(v.y), rneb(v.z), rneb(v.w) };
    reinterpret_cast<ushort4*>(xb)[g] = o;
}

// ---------- W f32 -> Wb bf16 ----------
__global__ void cvtw_k(const float* __restrict__ W, unsigned short* __restrict__ Wb) {
    int g = blockIdx.x * 256 + threadIdx.x;      // 8192 float4-groups
    if (g >= 128 * 64) return;
    float4 v = reinterpret_cast<const float4*>(W)[g];
    ushort4 o = { rneb(v.x), rneb(v.y), rneb(v.z), rneb(v.w) };
    reinterpret_cast<ushort4*>(Wb)[g] = o;
}

// ---------- coarse bucket count: 128 blocks x 5000 edges ----------
__global__ __launch_bounds__(1024) void ccount_k(const int* __restrict__ dst,
                                                 int* __restrict__ gcnt) {
    __shared__ int cnt[NBKT];
    int t = threadIdx.x;
    if (t < NBKT) cnt[t] = 0;
    __syncthreads();
    int eb = blockIdx.x * 5000;
    for (int i = t; i < 5000; i += 1024)
        atomicAdd(&cnt[dst[eb + i] >> 6], 1);
    __syncthreads();
    if (t < NBKT && cnt[t]) atomicAdd(&gcnt[t], cnt[t]);
}

// ---------- exclusive scan of 625 bucket counts -> bptr[626], cursor[625] ----------
__global__ __launch_bounds__(1024) void cscan_k(const int* __restrict__ gcnt,
                                                int* __restrict__ bptr,
                                                int* __restrict__ cursor) {
    __shared__ int sc[1024];
    int t = threadIdx.x;
    int c = (t < NBKT) ? gcnt[t] : 0;
    sc[t] = c;
    __syncthreads();
    for (int o = 1; o < 1024; o <<= 1) {
        int u = (t >= o) ? sc[t - o] : 0;
        __syncthreads();
        sc[t] += u;
        __syncthreads();
    }
    if (t < NBKT) {
        int excl = sc[t] - c;
        bptr[t]   = excl;
        cursor[t] = excl;
    }
    if (t == 0) bptr[NBKT] = NE;
}

// ---------- bucket scatter: rec {src u16 | ew f16}, dloc u8 ----------
__global__ __launch_bounds__(1024) void cscatter_k(const int* __restrict__ dst,
                                                   const int* __restrict__ src,
                                                   const float* __restrict__ ew,
                                                   int* __restrict__ cursor,
                                                   unsigned* __restrict__ rec,
                                                   unsigned char* __restrict__ dloc) {
    __shared__ int cnt[NBKT];
    __shared__ int base[NBKT];
    int t = threadIdx.x;
    if (t < NBKT) cnt[t] = 0;
    __syncthreads();
    int eb = blockIdx.x * 5000;
    for (int i = t; i < 5000; i += 1024)
        atomicAdd(&cnt[dst[eb + i] >> 6], 1);
    __syncthreads();
    if (t < NBKT) {
        base[t] = atomicAdd(&cursor[t], cnt[t]);   // reserve contiguous run
        cnt[t]  = 0;                               // reuse as local cursor
    }
    __syncthreads();
    for (int i = t; i < 5000; i += 1024) {
        int d   = dst[eb + i];
        int bkt = d >> 6;
        int slot = atomicAdd(&cnt[bkt], 1);
        int p = base[bkt] + slot;
        unsigned short wh = __builtin_bit_cast(unsigned short, (_Float16)ew[eb + i]);
        rec[p]  = (unsigned)src[eb + i] | ((unsigned)wh << 16);
        dloc[p] = (unsigned char)(d & 63);
    }
}

// ---------- bucket aggregate: in-LDS regroup by node, REGISTER accumulation ----------
// One block per bucket (64 nodes). Per chunk of <=2048 records:
//   count per-node (1 int LDS atomic/edge) -> wave-0 scan of 64 -> scatter to
//   grouped LDS order (1 int atomic + 1 LDS write/edge). Then 16-lane group g
//   walks node g's list: LDS broadcast read -> 256B coalesced xb-row gather ->
//   FMA into 8 f32 regs. Agg written f32 into d_out (gemm row-owns it).
__global__ __launch_bounds__(1024) void agg3_k(const unsigned* __restrict__ rec,
                                               const unsigned char* __restrict__ dloc,
                                               const int* __restrict__ bptr,
                                               const unsigned short* __restrict__ xb,
                                               float* __restrict__ out) {
    constexpr int CAP = 2048;
    __shared__ unsigned grec[CAP];
    __shared__ int cnt[64];
    __shared__ int cur[64];
    __shared__ int pL[65];
    int bkt = blockIdx.x, t = threadIdx.x;
    int beg = bptr[bkt], end = bptr[bkt + 1];
    int grp = t >> 4, fl = t & 15;     // 64 node-groups x 16 feature-lanes
    float acc[8] = {0.f, 0.f, 0.f, 0.f, 0.f, 0.f, 0.f, 0.f};
    float wsv = 0.f;

    for (int cb = beg; cb < end; cb += CAP) {
        int m = end - cb; if (m > CAP) m = CAP;
        if (t < 64) cnt[t] = 0;
        __syncthreads();
        unsigned r0 = 0, r1 = 0; int d0 = -1, d1 = -1;
        if (t < m)        { r0 = rec[cb + t];        d0 = dloc[cb + t];        atomicAdd(&cnt[d0], 1); }
        if (t + 1024 < m) { r1 = rec[cb + t + 1024]; d1 = dloc[cb + t + 1024]; atomicAdd(&cnt[d1], 1); }
        __syncthreads();
        if (t < 64) {                  // wave 0: inclusive scan of 64 counts
            int v = cnt[t], s = v;
            #pragma unroll
            for (int o = 1; o < 64; o <<= 1) {
                int u = __shfl_up(s, o);
                if (t >= o) s += u;
            }
            pL[t]  = s - v;
            cur[t] = s - v;
            if (t == 63) pL[64] = s;
        }
        __syncthreads();
        if (d0 >= 0) { int p = atomicAdd(&cur[d0], 1); grec[p] = r0; }
        if (d1 >= 0) { int p = atomicAdd(&cur[d1], 1); grec[p] = r1; }
        __syncthreads();
        int gb = pL[grp], ge = pL[grp + 1];
        for (int e = gb; e < ge; ++e) {
            unsigned r = grec[e];                       // broadcast within group
            int s = r & 0xFFFF;
            float w = (float)__builtin_bit_cast(_Float16, (unsigned short)(r >> 16));
            short8 v = *reinterpret_cast<const short8*>(xb + (size_t)s * 128 + fl * 8);
            wsv += w;
            #pragma unroll
            for (int i = 0; i < 8; ++i) acc[i] += w * b2f((unsigned short)v[i]);
        }
        __syncthreads();               // protect grec/cnt for next chunk
    }

    int n = bkt * 64 + grp;
    float inv = 1.f / fmaxf(wsv, 1e-8f);
    float4 o0 = { acc[0] * inv, acc[1] * inv, acc[2] * inv, acc[3] * inv };
    float4 o1 = { acc[4] * inv, acc[5] * inv, acc[6] * inv, acc[7] * inv };
    float4* op = reinterpret_cast<float4*>(out + (size_t)n * 128 + fl * 8);
    op[0] = o0;
    op[1] = o1;
}

// ---------- MFMA GEMM: out = [xb | agg(f32, in out)] @ Wb^T + b ----------
// Each block owns rows [rb, rb+128): reads agg only from its own rows, then
// overwrites them -> no cross-block race. (Verified in R5.)
__global__ __launch_bounds__(256) void gemm_mfma_k(const unsigned short* __restrict__ xb,
                                                   const unsigned short* __restrict__ Wb,
                                                   const float* __restrict__ bias_p,
                                                   float* out) {
    int w = threadIdx.x >> 6, l = threadIdx.x & 63;
    int l15 = l & 15, lg = l >> 4;
    int rb = blockIdx.x * 128 + w * 32;

    f32x4 acc[2][8];
    #pragma unroll
    for (int i = 0; i < 2; ++i)
        #pragma unroll
        for (int c = 0; c < 8; ++c) acc[i][c] = (f32x4)0.f;

    float bias[8];
    #pragma unroll
    for (int c = 0; c < 8; ++c) bias[c] = bias_p[c * 16 + l15];

    int r0 = rb + l15;      if (r0 > NN - 1) r0 = NN - 1;
    int r1 = rb + 16 + l15; if (r1 > NN - 1) r1 = NN - 1;

    #pragma unroll
    for (int step = 0; step < 8; ++step) {
        int kg = step * 32 + lg * 8;
        short8 a0, a1;
        if (step < 4) {
            a0 = *reinterpret_cast<const short8*>(xb + (size_t)r0 * 128 + kg);
            a1 = *reinterpret_cast<const short8*>(xb + (size_t)r1 * 128 + kg);
        } else {
            const float* p0 = out + (size_t)r0 * 128 + (kg - 128);
            const float* p1 = out + (size_t)r1 * 128 + (kg - 128);
            float4 u0 = *reinterpret_cast<const float4*>(p0);
            float4 u1 = *reinterpret_cast<const float4*>(p0 + 4);
            float4 v0 = *reinterpret_cast<const float4*>(p1);
            float4 v1 = *reinterpret_cast<const float4*>(p1 + 4);
            a0 = short8{ (short)rneb(u0.x), (short)rneb(u0.y), (short)rneb(u0.z), (short)rneb(u0.w),
                         (short)rneb(u1.x), (short)rneb(u1.y), (short)rneb(u1.z), (short)rneb(u1.w) };
            a1 = short8{ (short)rneb(v0.x), (short)rneb(v0.y), (short)rneb(v0.z), (short)rneb(v0.w),
                         (short)rneb(v1.x), (short)rneb(v1.y), (short)rneb(v1.z), (short)rneb(v1.w) };
        }
        #pragma unroll
        for (int c = 0; c < 8; ++c) {
            short8 bf = *reinterpret_cast<const short8*>(Wb + (size_t)(c * 16 + l15) * 256 + kg);
            acc[0][c] = __builtin_amdgcn_mfma_f32_16x16x32_bf16(a0, bf, acc[0][c], 0, 0, 0);
            acc[1][c] = __builtin_amdgcn_mfma_f32_16x16x32_bf16(a1, bf, acc[1][c], 0, 0, 0);
        }
    }

    #pragma unroll
    for (int i = 0; i < 2; ++i) {
        int rbase = rb + i * 16 + lg * 4;
        #pragma unroll
        for (int c = 0; c < 8; ++c) {
            #pragma unroll
            for (int r = 0; r < 4; ++r) {
                int row = rbase + r;
                if (row < NN)
                    out[(size_t)row * 128 + c * 16 + l15] = acc[i][c][r] + bias[c];
            }
        }
    }
}

// ==================== fallback path (small ws): atomic scatter + f32 GEMM ====================

__global__ void wsum_k(const int* __restrict__ dst, const float* __restrict__ ew,
                       float* __restrict__ wsum) {
    int e = blockIdx.x * 256 + threadIdx.x;
    if (e < NE) atomicAdd(&wsum[dst[e]], ew[e]);
}

__global__ void zerof_k(float* __restrict__ p, int n4) {
    int g = blockIdx.x * 256 + threadIdx.x;
    if (g < n4) reinterpret_cast<float4*>(p)[g] = make_float4(0.f, 0.f, 0.f, 0.f);
}

__global__ void scatter_k(const int* __restrict__ src, const int* __restrict__ dst,
                          const float* __restrict__ ew, const float* __restrict__ wsum,
                          const float* __restrict__ x, float* __restrict__ agg) {
    int tid = blockIdx.x * 256 + threadIdx.x;
    int e = tid >> 5;
    int p = tid & 31;
    if (e >= NE) return;
    int s = src[e], dn = dst[e];
    float wn = ew[e] / fmaxf(wsum[dn], 1e-8f);
    float4 v = *reinterpret_cast<const float4*>(x + (size_t)s * 128 + p * 4);
    float* o = agg + (size_t)dn * 128 + p * 4;
    atomicAdd(o + 0, wn * v.x);
    atomicAdd(o + 1, wn * v.y);
    atomicAdd(o + 2, wn * v.z);
    atomicAdd(o + 3, wn * v.w);
}

__global__ __launch_bounds__(256) void gemm_f32_k(const float* __restrict__ x,
                                                  const float* __restrict__ agg,
                                                  const float* __restrict__ W,
                                                  const float* __restrict__ b,
                                                  float* __restrict__ out) {
    __shared__ float4 Wl[128 * 64];
    __shared__ float4 hl[16 * 64];
    int t = threadIdx.x;
    int base = blockIdx.x * 80;
    const float4* Wg = reinterpret_cast<const float4*>(W);
    #pragma unroll
    for (int i = 0; i < 32; ++i) {
        int f = t + i * 256;
        int r = f >> 6, kk = f & 63;
        Wl[r * 64 + (kk ^ (r & 7))] = Wg[f];
    }
    int jj = t & 63, wsl = t >> 6, sw = jj & 7;
    float bv[2] = { b[jj], b[jj + 64] };
    const float4* xg = reinterpret_cast<const float4*>(x);
    const float4* ag = reinterpret_cast<const float4*>(agg);
    for (int g = 0; g < 5; ++g) {
        int nbase = base + g * 16;
        __syncthreads();
        #pragma unroll
        for (int i = 0; i < 4; ++i) {
            int f = t + i * 256;
            int ln = f >> 6, kk = f & 63;
            size_t node = (size_t)(nbase + ln);
            hl[ln * 64 + kk] = (kk < 32) ? xg[node * 32 + kk] : ag[node * 32 + (kk - 32)];
        }
        __syncthreads();
        float acc[2][4];
        #pragma unroll
        for (int q = 0; q < 2; ++q)
            #pragma unroll
            for (int n = 0; n < 4; ++n) acc[q][n] = 0.f;
        #pragma unroll 4
        for (int kk = 0; kk < 64; ++kk) {
            float4 h[4];
            #pragma unroll
            for (int n = 0; n < 4; ++n) h[n] = hl[(wsl + 4 * n) * 64 + kk];
            #pragma unroll
            for (int q = 0; q < 2; ++q) {
                float4 wv = Wl[(jj + q * 64) * 64 + (kk ^ sw)];
                #pragma unroll
                for (int n = 0; n < 4; ++n)
                    acc[q][n] += wv.x * h[n].x + wv.y * h[n].y + wv.z * h[n].z + wv.w * h[n].w;
            }
        }
        #pragma unroll
        for (int q = 0; q < 2; ++q)
            #pragma unroll
            for (int n = 0; n < 4; ++n)
                out[(size_t)(nbase + wsl + 4 * n) * 128 + jj + q * 64] = acc[q][n] + bv[q];
    }
}

extern "C" void kernel_launch(void* const* d_in, const int* in_sizes, int n_in,
                              void* d_out, int out_size, void* d_ws, size_t ws_size,
                              hipStream_t stream) {
    const float* x  = (const float*)d_in[0];
    const int*   ei = (const int*)d_in[1];
    const float* ew = (const float*)d_in[2];
    const float* W  = (const float*)d_in[3];
    const float* b  = (const float*)d_in[4];
    float* out = (float*)d_out;
    const int* src = ei;
    const int* dst = ei + NE;

    // ws layout (bytes):
    //   0        : bptr [626 int]
    //   4096     : cursor [625 int]
    //   8192     : gcnt [625 int]
    //   16384    : Wb [128x256 bf16] (64 KB)
    //   81920    : dloc [640000 u8]
    //   724992   : rec [640000 u32] (2.56 MB)
    //   3284992  : xb [40000][128] bf16 (10.24 MB)   -> need ~13.5 MB (proven in R5)
    const size_t off_cursor = 4096;
    const size_t off_gcnt   = 8192;
    const size_t off_Wb     = 16384;
    const size_t off_dloc   = 81920;
    const size_t off_rec    = 724992;
    const size_t off_xb     = 3284992;
    const size_t need = off_xb + (size_t)NN * 128 * 2;

    if (ws_size >= need) {
        int* bptr   = (int*)d_ws;
        int* cursor = (int*)((char*)d_ws + off_cursor);
        int* gcnt   = (int*)((char*)d_ws + off_gcnt);
        unsigned short* Wb = (unsigned short*)((char*)d_ws + off_Wb);
        unsigned char* dloc = (unsigned char*)((char*)d_ws + off_dloc);
        unsigned* rec = (unsigned*)((char*)d_ws + off_rec);
        unsigned short* xb = (unsigned short*)((char*)d_ws + off_xb);

        zero_k    <<<1, 1024, 0, stream>>>(gcnt);
        cvtx_k    <<<5000, 256, 0, stream>>>(x, xb);
        ccount_k  <<<128, 1024, 0, stream>>>(dst, gcnt);
        cscan_k   <<<1, 1024, 0, stream>>>(gcnt, bptr, cursor);
        cscatter_k<<<128, 1024, 0, stream>>>(dst, src, ew, cursor, rec, dloc);
        cvtw_k    <<<32, 256, 0, stream>>>(W, Wb);
        agg3_k    <<<NBKT, 1024, 0, stream>>>(rec, dloc, bptr, xb, out);
        gemm_mfma_k<<<(NN + 127) / 128, 256, 0, stream>>>(xb, Wb, b, out);
    } else {
        float* wsum = (float*)d_ws;
        float* agg  = out;
        zerof_k  <<<(NN / 4 + 255) / 256, 256, 0, stream>>>(wsum, NN / 4);
        zerof_k  <<<(NN * 32 + 255) / 256, 256, 0, stream>>>(agg, NN * 32);
        wsum_k   <<<(NE + 255) / 256, 256, 0, stream>>>(dst, ew, wsum);
        scatter_k<<<NE * 32 / 256, 256, 0, stream>>>(src, dst, ew, wsum, x, agg);
        gemm_f32_k<<<500, 256, 0, stream>>>(x, agg, W, b, out);
    }
}

// Round 7
// 92.189 us; speedup vs baseline: 6.3832x; 1.0527x over previous
//
#include <hip/hip_runtime.h>

constexpr int NN = 40000;
constexpr int NE = 640000;
constexpr int NBKT = 625;      // bucket = dst >> 6, 64 nodes per bucket; 625*64 == 40000
constexpr int CBLK = 128;      // count/scatter blocks; 128*5000 == NE

typedef __attribute__((ext_vector_type(8))) short short8;
typedef __attribute__((ext_vector_type(4))) float f32x4;

// f32 -> bf16 round-to-nearest-even
__device__ __forceinline__ unsigned short rneb(float f) {
    unsigned u = __float_as_uint(f);
    u = (u + 0x7FFFu + ((u >> 16) & 1u)) >> 16;
    return (unsigned short)u;
}
__device__ __forceinline__ float b2f(unsigned short s) {
    return __uint_as_float(((unsigned)s) << 16);
}

// ---------- K1: fused cvtx + cvtW + per-block bucket counts (no atomics to global) ----------
__global__ __launch_bounds__(1024) void prep_k(const float* __restrict__ x,
                                               unsigned short* __restrict__ xb,
                                               const float* __restrict__ W,
                                               unsigned short* __restrict__ Wb,
                                               const int* __restrict__ dst,
                                               int* __restrict__ gcnt2) {
    __shared__ int cnt[NBKT];
    int bid = blockIdx.x, t = threadIdx.x;
    if (bid < 1250) {                            // x: 1250*1024 == NN*32 f4-groups
        int g = bid * 1024 + t;
        float4 v = reinterpret_cast<const float4*>(x)[g];
        ushort4 o = { rneb(v.x), rneb(v.y), rneb(v.z), rneb(v.w) };
        reinterpret_cast<ushort4*>(xb)[g] = o;
    } else if (bid < 1258) {                     // W: 8*1024 == 128*256/4 f4-groups
        int g = (bid - 1250) * 1024 + t;
        float4 v = reinterpret_cast<const float4*>(W)[g];
        ushort4 o = { rneb(v.x), rneb(v.y), rneb(v.z), rneb(v.w) };
        reinterpret_cast<ushort4*>(Wb)[g] = o;
    } else {                                     // counts: 128 blocks x 5000 edges
        int cb = bid - 1258;
        if (t < NBKT) cnt[t] = 0;
        __syncthreads();
        int eb = cb * 5000;
        for (int i = t; i < 5000; i += 1024)
            atomicAdd(&cnt[dst[eb + i] >> 6], 1);
        __syncthreads();
        if (t < NBKT) gcnt2[cb * 640 + t] = cnt[t];
    }
}

// ---------- K2: sum per-block counts + exclusive scan -> bptr[626], cursor[625] ----------
__global__ __launch_bounds__(1024) void cscan_k(const int* __restrict__ gcnt2,
                                                int* __restrict__ bptr,
                                                int* __restrict__ cursor) {
    __shared__ int sc[1024];
    int t = threadIdx.x;
    int c = 0;
    if (t < NBKT)
        for (int b = 0; b < CBLK; ++b) c += gcnt2[b * 640 + t];
    sc[t] = c;
    __syncthreads();
    for (int o = 1; o < 1024; o <<= 1) {
        int u = (t >= o) ? sc[t - o] : 0;
        __syncthreads();
        sc[t] += u;
        __syncthreads();
    }
    if (t < NBKT) {
        int excl = sc[t] - c;
        bptr[t]   = excl;
        cursor[t] = excl;
    }
    if (t == 0) bptr[NBKT] = NE;
}

// ---------- K3: bucket scatter: rec {src u16 | ew f16}, dloc u8 (verified R5/R6) ----------
__global__ __launch_bounds__(1024) void cscatter_k(const int* __restrict__ dst,
                                                   const int* __restrict__ src,
                                                   const float* __restrict__ ew,
                                                   int* __restrict__ cursor,
                                                   unsigned* __restrict__ rec,
                                                   unsigned char* __restrict__ dloc) {
    __shared__ int cnt[NBKT];
    __shared__ int base[NBKT];
    int t = threadIdx.x;
    if (t < NBKT) cnt[t] = 0;
    __syncthreads();
    int eb = blockIdx.x * 5000;
    for (int i = t; i < 5000; i += 1024)
        atomicAdd(&cnt[dst[eb + i] >> 6], 1);
    __syncthreads();
    if (t < NBKT) {
        base[t] = atomicAdd(&cursor[t], cnt[t]);   // reserve contiguous run
        cnt[t]  = 0;                               // reuse as local cursor
    }
    __syncthreads();
    for (int i = t; i < 5000; i += 1024) {
        int d   = dst[eb + i];
        int bkt = d >> 6;
        int slot = atomicAdd(&cnt[bkt], 1);
        int p = base[bkt] + slot;
        unsigned short wh = __builtin_bit_cast(unsigned short, (_Float16)ew[eb + i]);
        rec[p]  = (unsigned)src[eb + i] | ((unsigned)wh << 16);
        dloc[p] = (unsigned char)(d & 63);
    }
}

// ---------- K4: fused aggregate + MFMA GEMM, one block per bucket ----------
// Phase 1 (== verified agg3): in-LDS regroup by node, register accumulation;
// result -> bf16 into XOR-swizzled LDS hbl[64 rows][128] (granule ^= row&7).
// Phase 2: out[row 0..63][0..127] = [xb_row | hbl_row] @ Wb^T + b via
// 16x16x32 MFMA; A x-half direct from global xb (L2-hot, verified pattern),
// A agg-half from swizzled LDS (2-way bank aliasing only). Block owns its
// 64 output rows -> race-free.
__global__ __launch_bounds__(1024) void aggemm_k(const unsigned* __restrict__ rec,
                                                 const unsigned char* __restrict__ dloc,
                                                 const int* __restrict__ bptr,
                                                 const unsigned short* __restrict__ xb,
                                                 const unsigned short* __restrict__ Wb,
                                                 const float* __restrict__ bias_p,
                                                 float* __restrict__ out) {
    constexpr int CAP = 2048;
    __shared__ unsigned grec[CAP];
    __shared__ int cnt[64];
    __shared__ int cur[64];
    __shared__ int pL[65];
    __shared__ unsigned short hbl[64 * 128];     // swizzled agg half, 16 KB
    int bkt = blockIdx.x, t = threadIdx.x;
    int beg = bptr[bkt], end = bptr[bkt + 1];
    int grp = t >> 4, fl = t & 15;               // 64 node-groups x 16 feature-lanes
    float acc[8] = {0.f, 0.f, 0.f, 0.f, 0.f, 0.f, 0.f, 0.f};
    float wsv = 0.f;

    for (int cb = beg; cb < end; cb += CAP) {
        int m = end - cb; if (m > CAP) m = CAP;
        if (t < 64) cnt[t] = 0;
        __syncthreads();
        unsigned r0 = 0, r1 = 0; int d0 = -1, d1 = -1;
        if (t < m)        { r0 = rec[cb + t];        d0 = dloc[cb + t];        atomicAdd(&cnt[d0], 1); }
        if (t + 1024 < m) { r1 = rec[cb + t + 1024]; d1 = dloc[cb + t + 1024]; atomicAdd(&cnt[d1], 1); }
        __syncthreads();
        if (t < 64) {                            // wave 0: inclusive scan of 64 counts
            int v = cnt[t], s = v;
            #pragma unroll
            for (int o = 1; o < 64; o <<= 1) {
                int u = __shfl_up(s, o);
                if (t >= o) s += u;
            }
            pL[t]  = s - v;
            cur[t] = s - v;
            if (t == 63) pL[64] = s;
        }
        __syncthreads();
        if (d0 >= 0) { int p = atomicAdd(&cur[d0], 1); grec[p] = r0; }
        if (d1 >= 0) { int p = atomicAdd(&cur[d1], 1); grec[p] = r1; }
        __syncthreads();
        int gb = pL[grp], ge = pL[grp + 1];
        for (int e = gb; e < ge; ++e) {
            unsigned r = grec[e];                // broadcast within group
            int s = r & 0xFFFF;
            float w = (float)__builtin_bit_cast(_Float16, (unsigned short)(r >> 16));
            short8 v = *reinterpret_cast<const short8*>(xb + (size_t)s * 128 + fl * 8);
            wsv += w;
            #pragma unroll
            for (int i = 0; i < 8; ++i) acc[i] += w * b2f((unsigned short)v[i]);
        }
        __syncthreads();                         // protect grec/cnt for next chunk
    }

    {   // write node grp's agg slice (bf16) into swizzled LDS
        float inv = 1.f / fmaxf(wsv, 1e-8f);
        short8 o;
        #pragma unroll
        for (int i = 0; i < 8; ++i) o[i] = (short)rneb(acc[i] * inv);
        int gs = fl ^ (grp & 7);                 // granule swizzle
        *reinterpret_cast<short8*>(&hbl[grp * 128 + gs * 8]) = o;
    }
    __syncthreads();

    // ---- phase 2: MFMA ----
    int w = t >> 6, l = t & 63;
    int l15 = l & 15, lg = l >> 4;
    int rt = w & 3, ct0 = w >> 2;                // wave -> row-tile, col-tiles {ct0, ct0+4}
    f32x4 acc2[2] = { (f32x4)0.f, (f32x4)0.f };
    float bias2[2] = { bias_p[ct0 * 16 + l15], bias_p[(ct0 + 4) * 16 + l15] };
    int arow = bkt * 64 + rt * 16 + l15;

    #pragma unroll
    for (int step = 0; step < 8; ++step) {
        short8 a;
        if (step < 4) {
            a = *reinterpret_cast<const short8*>(xb + (size_t)arow * 128 + step * 32 + lg * 8);
        } else {
            int r = rt * 16 + l15;
            int g = (step - 4) * 4 + lg;         // granule 0..15 in agg half
            a = *reinterpret_cast<const short8*>(&hbl[r * 128 + (g ^ (r & 7)) * 8]);
        }
        #pragma unroll
        for (int q = 0; q < 2; ++q) {
            int ct = ct0 + q * 4;
            short8 bf = *reinterpret_cast<const short8*>(Wb + (size_t)(ct * 16 + l15) * 256 + step * 32 + lg * 8);
            acc2[q] = __builtin_amdgcn_mfma_f32_16x16x32_bf16(a, bf, acc2[q], 0, 0, 0);
        }
    }

    #pragma unroll
    for (int q = 0; q < 2; ++q)
        #pragma unroll
        for (int r4 = 0; r4 < 4; ++r4) {
            int row = bkt * 64 + rt * 16 + lg * 4 + r4;
            out[(size_t)row * 128 + (ct0 + q * 4) * 16 + l15] = acc2[q][r4] + bias2[q];
        }
}

// ==================== fallback path (small ws): atomic scatter + f32 GEMM ====================

__global__ void wsum_k(const int* __restrict__ dst, const float* __restrict__ ew,
                       float* __restrict__ wsum) {
    int e = blockIdx.x * 256 + threadIdx.x;
    if (e < NE) atomicAdd(&wsum[dst[e]], ew[e]);
}

__global__ void zerof_k(float* __restrict__ p, int n4) {
    int g = blockIdx.x * 256 + threadIdx.x;
    if (g < n4) reinterpret_cast<float4*>(p)[g] = make_float4(0.f, 0.f, 0.f, 0.f);
}

__global__ void scatter_k(const int* __restrict__ src, const int* __restrict__ dst,
                          const float* __restrict__ ew, const float* __restrict__ wsum,
                          const float* __restrict__ x, float* __restrict__ agg) {
    int tid = blockIdx.x * 256 + threadIdx.x;
    int e = tid >> 5;
    int p = tid & 31;
    if (e >= NE) return;
    int s = src[e], dn = dst[e];
    float wn = ew[e] / fmaxf(wsum[dn], 1e-8f);
    float4 v = *reinterpret_cast<const float4*>(x + (size_t)s * 128 + p * 4);
    float* o = agg + (size_t)dn * 128 + p * 4;
    atomicAdd(o + 0, wn * v.x);
    atomicAdd(o + 1, wn * v.y);
    atomicAdd(o + 2, wn * v.z);
    atomicAdd(o + 3, wn * v.w);
}

__global__ __launch_bounds__(256) void gemm_f32_k(const float* __restrict__ x,
                                                  const float* __restrict__ agg,
                                                  const float* __restrict__ W,
                                                  const float* __restrict__ b,
                                                  float* __restrict__ out) {
    __shared__ float4 Wl[128 * 64];
    __shared__ float4 hl[16 * 64];
    int t = threadIdx.x;
    int base = blockIdx.x * 80;
    const float4* Wg = reinterpret_cast<const float4*>(W);
    #pragma unroll
    for (int i = 0; i < 32; ++i) {
        int f = t + i * 256;
        int r = f >> 6, kk = f & 63;
        Wl[r * 64 + (kk ^ (r & 7))] = Wg[f];
    }
    int jj = t & 63, wsl = t >> 6, sw = jj & 7;
    float bv[2] = { b[jj], b[jj + 64] };
    const float4* xg = reinterpret_cast<const float4*>(x);
    const float4* ag = reinterpret_cast<const float4*>(agg);
    for (int g = 0; g < 5; ++g) {
        int nbase = base + g * 16;
        __syncthreads();
        #pragma unroll
        for (int i = 0; i < 4; ++i) {
            int f = t + i * 256;
            int ln = f >> 6, kk = f & 63;
            size_t node = (size_t)(nbase + ln);
            hl[ln * 64 + kk] = (kk < 32) ? xg[node * 32 + kk] : ag[node * 32 + (kk - 32)];
        }
        __syncthreads();
        float acc[2][4];
        #pragma unroll
        for (int q = 0; q < 2; ++q)
            #pragma unroll
            for (int n = 0; n < 4; ++n) acc[q][n] = 0.f;
        #pragma unroll 4
        for (int kk = 0; kk < 64; ++kk) {
            float4 h[4];
            #pragma unroll
            for (int n = 0; n < 4; ++n) h[n] = hl[(wsl + 4 * n) * 64 + kk];
            #pragma unroll
            for (int q = 0; q < 2; ++q) {
                float4 wv = Wl[(jj + q * 64) * 64 + (kk ^ sw)];
                #pragma unroll
                for (int n = 0; n < 4; ++n)
                    acc[q][n] += wv.x * h[n].x + wv.y * h[n].y + wv.z * h[n].z + wv.w * h[n].w;
            }
        }
        #pragma unroll
        for (int q = 0; q < 2; ++q)
            #pragma unroll
            for (int n = 0; n < 4; ++n)
                out[(size_t)(nbase + wsl + 4 * n) * 128 + jj + q * 64] = acc[q][n] + bv[q];
    }
}

extern "C" void kernel_launch(void* const* d_in, const int* in_sizes, int n_in,
                              void* d_out, int out_size, void* d_ws, size_t ws_size,
                              hipStream_t stream) {
    const float* x  = (const float*)d_in[0];
    const int*   ei = (const int*)d_in[1];
    const float* ew = (const float*)d_in[2];
    const float* W  = (const float*)d_in[3];
    const float* b  = (const float*)d_in[4];
    float* out = (float*)d_out;
    const int* src = ei;
    const int* dst = ei + NE;

    // ws layout (bytes):
    //   0        : bptr [626 int]
    //   4096     : cursor [625 int]
    //   8192     : gcnt2 [128][640] int (327680) -> ends 335872
    //   339968   : Wb [128x256 bf16] (64 KB) -> ends 405504
    //   405504   : dloc [640000 u8] -> ends 1045504
    //   1048576  : rec [640000 u32] (2.56 MB) -> ends 3608576
    //   3670016  : xb [40000][128] bf16 (10.24 MB) -> need ~13.9 MB
    const size_t off_cursor = 4096;
    const size_t off_gcnt2  = 8192;
    const size_t off_Wb     = 339968;
    const size_t off_dloc   = 405504;
    const size_t off_rec    = 1048576;
    const size_t off_xb     = 3670016;
    const size_t need = off_xb + (size_t)NN * 128 * 2;

    if (ws_size >= need) {
        int* bptr   = (int*)d_ws;
        int* cursor = (int*)((char*)d_ws + off_cursor);
        int* gcnt2  = (int*)((char*)d_ws + off_gcnt2);
        unsigned short* Wb = (unsigned short*)((char*)d_ws + off_Wb);
        unsigned char* dloc = (unsigned char*)((char*)d_ws + off_dloc);
        unsigned* rec = (unsigned*)((char*)d_ws + off_rec);
        unsigned short* xb = (unsigned short*)((char*)d_ws + off_xb);

        prep_k    <<<1386, 1024, 0, stream>>>(x, xb, W, Wb, dst, gcnt2);
        cscan_k   <<<1, 1024, 0, stream>>>(gcnt2, bptr, cursor);
        cscatter_k<<<CBLK, 1024, 0, stream>>>(dst, src, ew, cursor, rec, dloc);
        aggemm_k  <<<NBKT, 1024, 0, stream>>>(rec, dloc, bptr, xb, Wb, b, out);
    } else {
        float* wsum = (float*)d_ws;
        float* agg  = out;
        zerof_k  <<<(NN / 4 + 255) / 256, 256, 0, stream>>>(wsum, NN / 4);
        zerof_k  <<<(NN * 32 + 255) / 256, 256, 0, stream>>>(agg, NN * 32);
        wsum_k   <<<(NE + 255) / 256, 256, 0, stream>>>(dst, ew, wsum);
        scatter_k<<<NE * 32 / 256, 256, 0, stream>>>(src, dst, ew, wsum, x, agg);
        gemm_f32_k<<<500, 256, 0, stream>>>(x, agg, W, b, out);
    }
}

// Round 8
// 91.068 us; speedup vs baseline: 6.4618x; 1.0123x over previous
//
#include <hip/hip_runtime.h>

constexpr int NN = 40000;
constexpr int NE = 640000;
constexpr int NBKT = 625;      // bucket = dst >> 6, 64 nodes per bucket; 625*64 == 40000
constexpr int CBLK = 128;      // count/scatter blocks; 128*5000 == NE

typedef __attribute__((ext_vector_type(8))) short short8;
typedef __attribute__((ext_vector_type(4))) float f32x4;

// f32 -> bf16 round-to-nearest-even
__device__ __forceinline__ unsigned short rneb(float f) {
    unsigned u = __float_as_uint(f);
    u = (u + 0x7FFFu + ((u >> 16) & 1u)) >> 16;
    return (unsigned short)u;
}
__device__ __forceinline__ float b2f(unsigned short s) {
    return __uint_as_float(((unsigned)s) << 16);
}

// ---------- K1: fused cvtx + cvtW + per-block bucket counts (no atomics to global) ----------
__global__ __launch_bounds__(1024) void prep_k(const float* __restrict__ x,
                                               unsigned short* __restrict__ xb,
                                               const float* __restrict__ W,
                                               unsigned short* __restrict__ Wb,
                                               const int* __restrict__ dst,
                                               int* __restrict__ gcnt2) {
    __shared__ int cnt[NBKT];
    int bid = blockIdx.x, t = threadIdx.x;
    if (bid < 1250) {                            // x: 1250*1024 == NN*32 f4-groups
        int g = bid * 1024 + t;
        float4 v = reinterpret_cast<const float4*>(x)[g];
        ushort4 o = { rneb(v.x), rneb(v.y), rneb(v.z), rneb(v.w) };
        reinterpret_cast<ushort4*>(xb)[g] = o;
    } else if (bid < 1258) {                     // W: 8*1024 == 128*256/4 f4-groups
        int g = (bid - 1250) * 1024 + t;
        float4 v = reinterpret_cast<const float4*>(W)[g];
        ushort4 o = { rneb(v.x), rneb(v.y), rneb(v.z), rneb(v.w) };
        reinterpret_cast<ushort4*>(Wb)[g] = o;
    } else {                                     // counts: 128 blocks x 5000 edges
        int cb = bid - 1258;
        if (t < NBKT) cnt[t] = 0;
        __syncthreads();
        int eb = cb * 5000;
        for (int i = t; i < 5000; i += 1024)
            atomicAdd(&cnt[dst[eb + i] >> 6], 1);
        __syncthreads();
        if (t < NBKT) gcnt2[cb * 640 + t] = cnt[t];
    }
}

// ---------- K2: sum per-block counts + exclusive scan -> bptr[626], cursor[625] ----------
__global__ __launch_bounds__(1024) void cscan_k(const int* __restrict__ gcnt2,
                                                int* __restrict__ bptr,
                                                int* __restrict__ cursor) {
    __shared__ int sc[1024];
    int t = threadIdx.x;
    int c = 0;
    if (t < NBKT)
        for (int b = 0; b < CBLK; ++b) c += gcnt2[b * 640 + t];
    sc[t] = c;
    __syncthreads();
    for (int o = 1; o < 1024; o <<= 1) {
        int u = (t >= o) ? sc[t - o] : 0;
        __syncthreads();
        sc[t] += u;
        __syncthreads();
    }
    if (t < NBKT) {
        int excl = sc[t] - c;
        bptr[t]   = excl;
        cursor[t] = excl;
    }
    if (t == 0) bptr[NBKT] = NE;
}

// ---------- K3: bucket scatter: rec {src u16 | ew f16}, dloc u8 (verified R5/R6) ----------
__global__ __launch_bounds__(1024) void cscatter_k(const int* __restrict__ dst,
                                                   const int* __restrict__ src,
                                                   const float* __restrict__ ew,
                                                   int* __restrict__ cursor,
                                                   unsigned* __restrict__ rec,
                                                   unsigned char* __restrict__ dloc) {
    __shared__ int cnt[NBKT];
    __shared__ int base[NBKT];
    int t = threadIdx.x;
    if (t < NBKT) cnt[t] = 0;
    __syncthreads();
    int eb = blockIdx.x * 5000;
    for (int i = t; i < 5000; i += 1024)
        atomicAdd(&cnt[dst[eb + i] >> 6], 1);
    __syncthreads();
    if (t < NBKT) {
        base[t] = atomicAdd(&cursor[t], cnt[t]);   // reserve contiguous run
        cnt[t]  = 0;                               // reuse as local cursor
    }
    __syncthreads();
    for (int i = t; i < 5000; i += 1024) {
        int d   = dst[eb + i];
        int bkt = d >> 6;
        int slot = atomicAdd(&cnt[bkt], 1);
        int p = base[bkt] + slot;
        unsigned short wh = __builtin_bit_cast(unsigned short, (_Float16)ew[eb + i]);
        rec[p]  = (unsigned)src[eb + i] | ((unsigned)wh << 16);
        dloc[p] = (unsigned char)(d & 63);
    }
}

// ---------- K4: fused aggregate + MFMA GEMM, one block per bucket ----------
// Phase 1: in-LDS regroup by node (verified R6/R7), then UNROLL-4 gather loop:
// 4 grec reads -> 4 independent 256B row-gathers in flight -> FMA. Breaks the
// one-outstanding-load-per-wave serialization that capped R7 at ~2.8 TB/s.
// Result -> bf16 into XOR-swizzled LDS. Phase 2: 64x256x128 MFMA (verified R7).
__global__ __launch_bounds__(1024) void aggemm_k(const unsigned* __restrict__ rec,
                                                 const unsigned char* __restrict__ dloc,
                                                 const int* __restrict__ bptr,
                                                 const unsigned short* __restrict__ xb,
                                                 const unsigned short* __restrict__ Wb,
                                                 const float* __restrict__ bias_p,
                                                 float* __restrict__ out) {
    constexpr int CAP = 2048;
    __shared__ unsigned grec[CAP];
    __shared__ int cnt[64];
    __shared__ int cur[64];
    __shared__ int pL[65];
    __shared__ unsigned short hbl[64 * 128];     // swizzled agg half, 16 KB
    int bkt = blockIdx.x, t = threadIdx.x;
    int beg = bptr[bkt], end = bptr[bkt + 1];
    int grp = t >> 4, fl = t & 15;               // 64 node-groups x 16 feature-lanes
    const short8* xv = reinterpret_cast<const short8*>(xb);   // row stride 16 short8
    float acc[8] = {0.f, 0.f, 0.f, 0.f, 0.f, 0.f, 0.f, 0.f};
    float wsv = 0.f;

    for (int cb = beg; cb < end; cb += CAP) {
        int m = end - cb; if (m > CAP) m = CAP;
        if (t < 64) cnt[t] = 0;
        __syncthreads();
        unsigned r0 = 0, r1 = 0; int d0 = -1, d1 = -1;
        if (t < m)        { r0 = rec[cb + t];        d0 = dloc[cb + t];        atomicAdd(&cnt[d0], 1); }
        if (t + 1024 < m) { r1 = rec[cb + t + 1024]; d1 = dloc[cb + t + 1024]; atomicAdd(&cnt[d1], 1); }
        __syncthreads();
        if (t < 64) {                            // wave 0: inclusive scan of 64 counts
            int v = cnt[t], s = v;
            #pragma unroll
            for (int o = 1; o < 64; o <<= 1) {
                int u = __shfl_up(s, o);
                if (t >= o) s += u;
            }
            pL[t]  = s - v;
            cur[t] = s - v;
            if (t == 63) pL[64] = s;
        }
        __syncthreads();
        if (d0 >= 0) { int p = atomicAdd(&cur[d0], 1); grec[p] = r0; }
        if (d1 >= 0) { int p = atomicAdd(&cur[d1], 1); grec[p] = r1; }
        __syncthreads();
        int gb = pL[grp], ge = pL[grp + 1];
        int e = gb;
        for (; e + 4 <= ge; e += 4) {            // UNROLL-4: 4 gathers in flight
            unsigned q0 = grec[e], q1 = grec[e + 1], q2 = grec[e + 2], q3 = grec[e + 3];
            short8 v0 = xv[(size_t)(q0 & 0xFFFF) * 16 + fl];
            short8 v1 = xv[(size_t)(q1 & 0xFFFF) * 16 + fl];
            short8 v2 = xv[(size_t)(q2 & 0xFFFF) * 16 + fl];
            short8 v3 = xv[(size_t)(q3 & 0xFFFF) * 16 + fl];
            float w0 = (float)__builtin_bit_cast(_Float16, (unsigned short)(q0 >> 16));
            float w1 = (float)__builtin_bit_cast(_Float16, (unsigned short)(q1 >> 16));
            float w2 = (float)__builtin_bit_cast(_Float16, (unsigned short)(q2 >> 16));
            float w3 = (float)__builtin_bit_cast(_Float16, (unsigned short)(q3 >> 16));
            wsv += w0 + w1 + w2 + w3;
            #pragma unroll
            for (int i = 0; i < 8; ++i)
                acc[i] += w0 * b2f((unsigned short)v0[i]) + w1 * b2f((unsigned short)v1[i])
                        + w2 * b2f((unsigned short)v2[i]) + w3 * b2f((unsigned short)v3[i]);
        }
        for (; e < ge; ++e) {                    // remainder (<=3)
            unsigned q = grec[e];
            short8 v = xv[(size_t)(q & 0xFFFF) * 16 + fl];
            float w = (float)__builtin_bit_cast(_Float16, (unsigned short)(q >> 16));
            wsv += w;
            #pragma unroll
            for (int i = 0; i < 8; ++i) acc[i] += w * b2f((unsigned short)v[i]);
        }
        __syncthreads();                         // protect grec/cnt for next chunk
    }

    {   // write node grp's agg slice (bf16) into swizzled LDS
        float inv = 1.f / fmaxf(wsv, 1e-8f);
        short8 o;
        #pragma unroll
        for (int i = 0; i < 8; ++i) o[i] = (short)rneb(acc[i] * inv);
        int gs = fl ^ (grp & 7);                 // granule swizzle
        *reinterpret_cast<short8*>(&hbl[grp * 128 + gs * 8]) = o;
    }
    __syncthreads();

    // ---- phase 2: MFMA ----
    int w = t >> 6, l = t & 63;
    int l15 = l & 15, lg = l >> 4;
    int rt = w & 3, ct0 = w >> 2;                // wave -> row-tile, col-tiles {ct0, ct0+4}
    f32x4 acc2[2] = { (f32x4)0.f, (f32x4)0.f };
    float bias2[2] = { bias_p[ct0 * 16 + l15], bias_p[(ct0 + 4) * 16 + l15] };
    int arow = bkt * 64 + rt * 16 + l15;

    #pragma unroll
    for (int step = 0; step < 8; ++step) {
        short8 a;
        if (step < 4) {
            a = *reinterpret_cast<const short8*>(xb + (size_t)arow * 128 + step * 32 + lg * 8);
        } else {
            int r = rt * 16 + l15;
            int g = (step - 4) * 4 + lg;         // granule 0..15 in agg half
            a = *reinterpret_cast<const short8*>(&hbl[r * 128 + (g ^ (r & 7)) * 8]);
        }
        #pragma unroll
        for (int q = 0; q < 2; ++q) {
            int ct = ct0 + q * 4;
            short8 bf = *reinterpret_cast<const short8*>(Wb + (size_t)(ct * 16 + l15) * 256 + step * 32 + lg * 8);
            acc2[q] = __builtin_amdgcn_mfma_f32_16x16x32_bf16(a, bf, acc2[q], 0, 0, 0);
        }
    }

    #pragma unroll
    for (int q = 0; q < 2; ++q)
        #pragma unroll
        for (int r4 = 0; r4 < 4; ++r4) {
            int row = bkt * 64 + rt * 16 + lg * 4 + r4;
            out[(size_t)row * 128 + (ct0 + q * 4) * 16 + l15] = acc2[q][r4] + bias2[q];
        }
}

// ==================== fallback path (small ws): atomic scatter + f32 GEMM ====================

__global__ void wsum_k(const int* __restrict__ dst, const float* __restrict__ ew,
                       float* __restrict__ wsum) {
    int e = blockIdx.x * 256 + threadIdx.x;
    if (e < NE) atomicAdd(&wsum[dst[e]], ew[e]);
}

__global__ void zerof_k(float* __restrict__ p, int n4) {
    int g = blockIdx.x * 256 + threadIdx.x;
    if (g < n4) reinterpret_cast<float4*>(p)[g] = make_float4(0.f, 0.f, 0.f, 0.f);
}

__global__ void scatter_k(const int* __restrict__ src, const int* __restrict__ dst,
                          const float* __restrict__ ew, const float* __restrict__ wsum,
                          const float* __restrict__ x, float* __restrict__ agg) {
    int tid = blockIdx.x * 256 + threadIdx.x;
    int e = tid >> 5;
    int p = tid & 31;
    if (e >= NE) return;
    int s = src[e], dn = dst[e];
    float wn = ew[e] / fmaxf(wsum[dn], 1e-8f);
    float4 v = *reinterpret_cast<const float4*>(x + (size_t)s * 128 + p * 4);
    float* o = agg + (size_t)dn * 128 + p * 4;
    atomicAdd(o + 0, wn * v.x);
    atomicAdd(o + 1, wn * v.y);
    atomicAdd(o + 2, wn * v.z);
    atomicAdd(o + 3, wn * v.w);
}

__global__ __launch_bounds__(256) void gemm_f32_k(const float* __restrict__ x,
                                                  const float* __restrict__ agg,
                                                  const float* __restrict__ W,
                                                  const float* __restrict__ b,
                                                  float* __restrict__ out) {
    __shared__ float4 Wl[128 * 64];
    __shared__ float4 hl[16 * 64];
    int t = threadIdx.x;
    int base = blockIdx.x * 80;
    const float4* Wg = reinterpret_cast<const float4*>(W);
    #pragma unroll
    for (int i = 0; i < 32; ++i) {
        int f = t + i * 256;
        int r = f >> 6, kk = f & 63;
        Wl[r * 64 + (kk ^ (r & 7))] = Wg[f];
    }
    int jj = t & 63, wsl = t >> 6, sw = jj & 7;
    float bv[2] = { b[jj], b[jj + 64] };
    const float4* xg = reinterpret_cast<const float4*>(x);
    const float4* ag = reinterpret_cast<const float4*>(agg);
    for (int g = 0; g < 5; ++g) {
        int nbase = base + g * 16;
        __syncthreads();
        #pragma unroll
        for (int i = 0; i < 4; ++i) {
            int f = t + i * 256;
            int ln = f >> 6, kk = f & 63;
            size_t node = (size_t)(nbase + ln);
            hl[ln * 64 + kk] = (kk < 32) ? xg[node * 32 + kk] : ag[node * 32 + (kk - 32)];
        }
        __syncthreads();
        float acc[2][4];
        #pragma unroll
        for (int q = 0; q < 2; ++q)
            #pragma unroll
            for (int n = 0; n < 4; ++n) acc[q][n] = 0.f;
        #pragma unroll 4
        for (int kk = 0; kk < 64; ++kk) {
            float4 h[4];
            #pragma unroll
            for (int n = 0; n < 4; ++n) h[n] = hl[(wsl + 4 * n) * 64 + kk];
            #pragma unroll
            for (int q = 0; q < 2; ++q) {
                float4 wv = Wl[(jj + q * 64) * 64 + (kk ^ sw)];
                #pragma unroll
                for (int n = 0; n < 4; ++n)
                    acc[q][n] += wv.x * h[n].x + wv.y * h[n].y + wv.z * h[n].z + wv.w * h[n].w;
            }
        }
        #pragma unroll
        for (int q = 0; q < 2; ++q)
            #pragma unroll
            for (int n = 0; n < 4; ++n)
                out[(size_t)(nbase + wsl + 4 * n) * 128 + jj + q * 64] = acc[q][n] + bv[q];
    }
}

extern "C" void kernel_launch(void* const* d_in, const int* in_sizes, int n_in,
                              void* d_out, int out_size, void* d_ws, size_t ws_size,
                              hipStream_t stream) {
    const float* x  = (const float*)d_in[0];
    const int*   ei = (const int*)d_in[1];
    const float* ew = (const float*)d_in[2];
    const float* W  = (const float*)d_in[3];
    const float* b  = (const float*)d_in[4];
    float* out = (float*)d_out;
    const int* src = ei;
    const int* dst = ei + NE;

    // ws layout (bytes):
    //   0        : bptr [626 int]
    //   4096     : cursor [625 int]
    //   8192     : gcnt2 [128][640] int (327680) -> ends 335872
    //   339968   : Wb [128x256 bf16] (64 KB) -> ends 405504
    //   405504   : dloc [640000 u8] -> ends 1045504
    //   1048576  : rec [640000 u32] (2.56 MB) -> ends 3608576
    //   3670016  : xb [40000][128] bf16 (10.24 MB) -> need ~13.9 MB
    const size_t off_cursor = 4096;
    const size_t off_gcnt2  = 8192;
    const size_t off_Wb     = 339968;
    const size_t off_dloc   = 405504;
    const size_t off_rec    = 1048576;
    const size_t off_xb     = 3670016;
    const size_t need = off_xb + (size_t)NN * 128 * 2;

    if (ws_size >= need) {
        int* bptr   = (int*)d_ws;
        int* cursor = (int*)((char*)d_ws + off_cursor);
        int* gcnt2  = (int*)((char*)d_ws + off_gcnt2);
        unsigned short* Wb = (unsigned short*)((char*)d_ws + off_Wb);
        unsigned char* dloc = (unsigned char*)((char*)d_ws + off_dloc);
        unsigned* rec = (unsigned*)((char*)d_ws + off_rec);
        unsigned short* xb = (unsigned short*)((char*)d_ws + off_xb);

        prep_k    <<<1386, 1024, 0, stream>>>(x, xb, W, Wb, dst, gcnt2);
        cscan_k   <<<1, 1024, 0, stream>>>(gcnt2, bptr, cursor);
        cscatter_k<<<CBLK, 1024, 0, stream>>>(dst, src, ew, cursor, rec, dloc);
        aggemm_k  <<<NBKT, 1024, 0, stream>>>(rec, dloc, bptr, xb, Wb, b, out);
    } else {
        float* wsum = (float*)d_ws;
        float* agg  = out;
        zerof_k  <<<(NN / 4 + 255) / 256, 256, 0, stream>>>(wsum, NN / 4);
        zerof_k  <<<(NN * 32 + 255) / 256, 256, 0, stream>>>(agg, NN * 32);
        wsum_k   <<<(NE + 255) / 256, 256, 0, stream>>>(dst, ew, wsum);
        scatter_k<<<NE * 32 / 256, 256, 0, stream>>>(src, dst, ew, wsum, x, agg);
        gemm_f32_k<<<500, 256, 0, stream>>>(x, agg, W, b, out);
    }
}